// Round 2
// baseline (4659.173 us; speedup 1.0000x reference)
//
#include <hip/hip_runtime.h>
#include <math.h>

#define Hd 512
#define Bd 64
#define Pd 32
#define Rd 4
#define Wd 64
#define NBLK 256

__device__ __forceinline__ float tanh_fast(float x) {
    float e = __expf(x + x);
    return 1.f - __fdividef(2.f, 1.f + e);
}

// ---------------- build WA = [W_a | lin_w^T]  (512 x 1024) ----------------
__global__ void k_prep_wa(const float* __restrict__ Wa, const float* __restrict__ lin_w,
                          float* __restrict__ WAc) {
    __shared__ float tile[32][33];
    int bx = blockIdx.x, by = blockIdx.y;
    int lane = threadIdx.x & 31, ty = threadIdx.x >> 5;
    for (int k = 0; k < 32; k += 8) {
        int y = by * 32 + ty + k;
        WAc[(size_t)y * 1024 + bx * 32 + lane] = Wa[(size_t)y * Hd + bx * 32 + lane];
    }
    int x = bx * 32 + lane;
    for (int k = 0; k < 32; k += 8) {
        int y = by * 32 + ty + k;
        tile[ty + k][lane] = lin_w[(size_t)y * Hd + x];
    }
    __syncthreads();
    int xo = by * 32 + lane;
    for (int k = 0; k < 32; k += 8) {
        int yo = bx * 32 + ty + k;
        WAc[(size_t)yo * 1024 + 512 + xo] = tile[lane][ty + k];
    }
}

// ---------------- Wctx[b,p,k] = sum_h ctx[b,p,h] * Wc[h,k] ----------------
__global__ void k_wctx(const float* __restrict__ ctx_pbh, const float* __restrict__ Wc,
                       float* __restrict__ Wctx) {
    __shared__ float As[16][Hd];
    int r0 = blockIdx.x * 16;
    int tid = threadIdx.x;
    for (int rr = 0; rr < 16; ++rr) {
        int bp = r0 + rr;
        int b = bp >> 5, p = bp & 31;
        const float* src = ctx_pbh + ((size_t)p * Bd + b) * Hd;
        for (int h = tid; h < Hd; h += 256) As[rr][h] = src[h];
    }
    __syncthreads();
    int c0 = tid, c1 = tid + 256;
    float acc0[16], acc1[16];
    #pragma unroll
    for (int rr = 0; rr < 16; ++rr) { acc0[rr] = 0.f; acc1[rr] = 0.f; }
    for (int h = 0; h < Hd; ++h) {
        float w0 = Wc[(size_t)h * Hd + c0], w1 = Wc[(size_t)h * Hd + c1];
        #pragma unroll
        for (int rr = 0; rr < 16; ++rr) {
            float a = As[rr][h];
            acc0[rr] += a * w0;
            acc1[rr] += a * w1;
        }
    }
    for (int rr = 0; rr < 16; ++rr) {
        Wctx[(size_t)(r0 + rr) * Hd + c0] = acc0[rr];
        Wctx[(size_t)(r0 + rr) * Hd + c1] = acc1[rr];
    }
}

// ---------------- rw[t*256+row][k] = sum_h resp[r,t,b,h] * Wt[h,k] ----------------
__global__ __launch_bounds__(256) void k_rw(const float* __restrict__ resp,
                                            const float* __restrict__ Wt,
                                            float* __restrict__ rw) {
    __shared__ float As[16][Hd];
    int gr0 = blockIdx.x * 16;
    int tid = threadIdx.x;
    for (int rr = 0; rr < 16; ++rr) {
        int gr = gr0 + rr;
        int t = gr >> 8, row = gr & 255;
        int r = row >> 6, bb = row & 63;
        const float* src = resp + (((size_t)(r * Wd + t)) * Bd + bb) * Hd;
        for (int h = tid; h < Hd; h += 256) As[rr][h] = src[h];
    }
    __syncthreads();
    int c0 = tid, c1 = tid + 256;
    float acc0[16], acc1[16];
    #pragma unroll
    for (int rr = 0; rr < 16; ++rr) { acc0[rr] = 0.f; acc1[rr] = 0.f; }
    for (int h = 0; h < Hd; ++h) {
        float w0 = Wt[(size_t)h * Hd + c0], w1 = Wt[(size_t)h * Hd + c1];
        #pragma unroll
        for (int rr = 0; rr < 16; ++rr) {
            float a = As[rr][h];
            acc0[rr] += a * w0;
            acc1[rr] += a * w1;
        }
    }
    for (int rr = 0; rr < 16; ++rr) {
        rw[(size_t)(gr0 + rr) * Hd + c0] = acc0[rr];
        rw[(size_t)(gr0 + rr) * Hd + c1] = acc1[rr];
    }
}

// ---------------- device-scope grid barrier (sense-reversing) ----------------
__device__ __forceinline__ void grid_barrier(unsigned* bar) {
    __syncthreads();
    if (threadIdx.x == 0) {
        __threadfence();                    // release prior writes (device scope)
        volatile unsigned* vcnt = bar;
        volatile unsigned* vgen = bar + 1;
        unsigned g = *vgen;
        unsigned arrived = atomicAdd(bar, 1u);
        if (arrived == NBLK - 1) {
            *vcnt = 0u;
            __threadfence();
            atomicAdd((unsigned*)(bar + 1), 1u);
        } else {
            while (*vgen == g) { __builtin_amdgcn_s_sleep(2); }
        }
        __threadfence();                    // acquire (invalidates L1)
    }
    __syncthreads();
}

// ---------------- cooperative persistent scan: 256 blocks x 512 threads ----------------
// Per block: phase-1 = one 32x32 tile of  atten_all(256x512) @ WA(512x1024),
//            with its 512x32 WA column-slice resident in LDS for the whole scan;
// phase-2 = softmax/score/atten-update for its own (r,b) row.
// Two grid barriers per timestep.
__global__ __launch_bounds__(512) void k_scan(
    const float* __restrict__ ctx,      // (P,B,H)
    const float* __restrict__ rw,       // (W*256, H)
    const float* __restrict__ WAc,      // (H, 1024)
    const float* __restrict__ Wctx,     // (B*P, H)
    const float* __restrict__ walpha,   // (H)
    const float* __restrict__ hidden,   // (R,B,H)
    const float* __restrict__ lin_p,    // (H,H)
    const float* __restrict__ lin_x,    // (H,H)
    float* __restrict__ out_resp,       // (R,B,H)
    float* __restrict__ out_alpha,      // (R,W,B,P)
    float* __restrict__ w_glob,         // (256,1024) scratch (aliases WAc)
    float* __restrict__ atten_g,        // (256,512)  scratch (aliases WAc)
    unsigned* __restrict__ bar)         // 2 u32
{
    extern __shared__ float dynS[];
    float* sWA  = dynS;                 // [512][32]   64 KB, persistent WA slice
    float* attC = dynS + 16384;         // [32][260] staging  /  [8][1024] partials (33.3 KB)

    __shared__ float wS[1024];
    __shared__ float attS[Hd];
    __shared__ float walS[Hd];
    __shared__ float scS[Pd];
    __shared__ float alS[Pd];

    const int tid = threadIdx.x;
    const int bid = blockIdx.x;

    // phase-1 identity: 8 cg (4 cols) x 8 rg (4 rows) x 8 hs (32-h window per chunk)
    const int cg = tid & 7;
    const int c4 = cg * 4;
    const int rg = (tid >> 3) & 7;
    const int r0 = rg * 4;
    const int hs = tid >> 6;
    const int rowbase = (bid >> 5) * 32;
    const int colbase = (bid & 31) * 32;

    // phase-2 identity
    const int r_ = bid >> 6;
    const int b_ = bid & 63;

    // preamble: WA slice -> LDS (reads complete before first barrier, so the
    // w_glob/atten_g aliases into WAc are safe); walpha -> LDS
    for (int i = tid; i < 16384; i += 512) {
        int h = i >> 5, c = i & 31;
        sWA[i] = WAc[(size_t)h * 1024 + colbase + c];
    }
    if (tid < Hd) walS[tid] = walpha[tid];
    __syncthreads();

    for (int t = 0; t < Wd; ++t) {
        // ================= phase 1: w tile = atten_tile @ WA_slice =================
        if (t > 0) {
            float acc[4][4];
            #pragma unroll
            for (int i = 0; i < 4; ++i) { acc[i][0]=0.f; acc[i][1]=0.f; acc[i][2]=0.f; acc[i][3]=0.f; }
            #pragma unroll 1
            for (int ch = 0; ch < 2; ++ch) {
                // stage atten tile chunk [32 rows][256 h], XOR-swizzled by (row>>2)&7
                #pragma unroll
                for (int k = 0; k < 4; ++k) {
                    int idx = (tid + (k << 9)) << 2;           // 0..8188
                    int rr = idx >> 8, hh = idx & 255;
                    float4 v = *(const float4*)&atten_g[(size_t)(rowbase + rr) * Hd + (ch << 8) + hh];
                    *(float4*)&attC[rr * 260 + (hh ^ (((rr >> 2) & 7) << 2))] = v;
                }
                __syncthreads();
                const int hbase = (ch << 8) + hs * 32;
                const int swz = rg << 2;                        // ((row>>2)&7)<<2, rows r0..r0+3 share rg
                #pragma unroll
                for (int hh4 = 0; hh4 < 32; hh4 += 4) {
                    const float* wp = sWA + (size_t)(hbase + hh4) * 32 + c4;
                    float4 w0 = *(const float4*)(wp);
                    float4 w1 = *(const float4*)(wp + 32);
                    float4 w2 = *(const float4*)(wp + 64);
                    float4 w3 = *(const float4*)(wp + 96);
                    const int hl = (hs * 32 + hh4) ^ swz;
                    #pragma unroll
                    for (int rr = 0; rr < 4; ++rr) {
                        float4 av = *(const float4*)&attC[(r0 + rr) * 260 + hl];
                        acc[rr][0] += av.x*w0.x + av.y*w1.x + av.z*w2.x + av.w*w3.x;
                        acc[rr][1] += av.x*w0.y + av.y*w1.y + av.z*w2.y + av.w*w3.y;
                        acc[rr][2] += av.x*w0.z + av.y*w1.z + av.z*w2.z + av.w*w3.z;
                        acc[rr][3] += av.x*w0.w + av.y*w1.w + av.z*w2.w + av.w*w3.w;
                    }
                }
                __syncthreads();
            }
            // partials (swizzled to avoid 8-way bank conflict) -> reduce -> w_glob
            #pragma unroll
            for (int rr = 0; rr < 4; ++rr) {
                int rowa = r0 + rr;
                float4 v = make_float4(acc[rr][0], acc[rr][1], acc[rr][2], acc[rr][3]);
                *(float4*)&attC[(hs << 10) + rowa * 32 + (c4 ^ ((rowa & 7) << 2))] = v;
            }
            __syncthreads();
            {
                const int oc2 = tid << 1;                       // 0..1022
                const int row = oc2 >> 5, c0 = oc2 & 31;
                const int pc = ((c0 & 28) ^ ((row & 7) << 2)) | (c0 & 3);
                float2 s = make_float2(0.f, 0.f);
                #pragma unroll
                for (int q = 0; q < 8; ++q) {
                    float2 p = *(const float2*)&attC[(q << 10) + row * 32 + pc];
                    s.x += p.x; s.y += p.y;
                }
                *(float2*)&w_glob[(size_t)(rowbase + row) * 1024 + colbase + c0] = s;
            }
        }
        grid_barrier(bar);

        // ================= phase 2: score / softmax / atten update for row bid =================
        {
            const float* rwrow = rw + ((size_t)(t * 256) + bid) * Hd;
            if (t > 0) {
                const float* wg = w_glob + (size_t)bid * 1024;
                for (int i = tid; i < 1024; i += 512)
                    wS[i] = (i < Hd) ? (wg[i] + rwrow[i]) : wg[i];
            } else {
                for (int i = tid; i < 1024; i += 512)
                    wS[i] = (i < Hd) ? rwrow[i] : 0.f;
            }
            __syncthreads();
            // score[p] = sum_h tanh(Wctx[b,p,h]+w[h])*walpha[h]  (16 threads per p)
            {
                const int p = tid >> 4, l16 = tid & 15;
                const float* wc = Wctx + ((size_t)(b_ * Pd + p)) * Hd;
                float sc = 0.f;
                #pragma unroll 4
                for (int k = 0; k < 8; ++k) {
                    int h4 = ((k << 4) + l16) << 2;
                    float4 wcv = *(const float4*)(wc + h4);
                    float4 wv  = *(const float4*)&wS[h4];
                    float4 wl  = *(const float4*)&walS[h4];
                    sc += tanh_fast(wcv.x + wv.x) * wl.x + tanh_fast(wcv.y + wv.y) * wl.y
                        + tanh_fast(wcv.z + wv.z) * wl.z + tanh_fast(wcv.w + wv.w) * wl.w;
                }
                sc += __shfl_down(sc, 8, 16);
                sc += __shfl_down(sc, 4, 16);
                sc += __shfl_down(sc, 2, 16);
                sc += __shfl_down(sc, 1, 16);
                if (l16 == 0) scS[p] = sc;
            }
            __syncthreads();
            if (tid < 32) {
                float s = scS[tid], m = s;
                #pragma unroll
                for (int off = 16; off; off >>= 1) m = fmaxf(m, __shfl_xor(m, off, 32));
                float e = __expf(s - m), sum = e;
                #pragma unroll
                for (int off = 16; off; off >>= 1) sum += __shfl_xor(sum, off, 32);
                float al = e * __fdividef(1.f, sum);
                alS[tid] = al;
                out_alpha[(((size_t)r_ * Wd + t) * Bd + b_) * Pd + tid] = al;
            }
            __syncthreads();
            {
                const int h = tid;                              // one h per thread
                float a = 0.f;
                #pragma unroll 8
                for (int pp = 0; pp < Pd; ++pp)
                    a += alS[pp] * ctx[((size_t)(pp * Bd + b_)) * Hd + h];
                a += tanh_fast(wS[Hd + h]);
                attS[h] = a;
                atten_g[(size_t)bid * Hd + h] = a;
            }
        }
        grid_barrier(bar);
    }

    // ---- epilogue: resp_c row = tanh(atten@lin_p^T + hidden@lin_x^T) ----
    if (tid < Hd) wS[tid] = hidden[((size_t)r_ * Bd + b_) * Hd + tid];
    __syncthreads();
    {
        const int wid = tid >> 6, lane = tid & 63;
        const int h8 = lane << 3;
        float4 a0 = *(const float4*)&attS[h8];
        float4 a1 = *(const float4*)&attS[h8 + 4];
        float4 q0 = *(const float4*)&wS[h8];
        float4 q1 = *(const float4*)&wS[h8 + 4];
        for (int k = 0; k < 64; ++k) {
            const int c = (wid << 6) + k;
            const float* lp = lin_p + (size_t)c * Hd + h8;
            const float* lx = lin_x + (size_t)c * Hd + h8;
            float4 p0 = *(const float4*)lp;
            float4 p1 = *(const float4*)(lp + 4);
            float4 x0 = *(const float4*)lx;
            float4 x1 = *(const float4*)(lx + 4);
            float s = a0.x*p0.x + a0.y*p0.y + a0.z*p0.z + a0.w*p0.w
                    + a1.x*p1.x + a1.y*p1.y + a1.z*p1.z + a1.w*p1.w
                    + q0.x*x0.x + q0.y*x0.y + q0.z*x0.z + q0.w*x0.w
                    + q1.x*x1.x + q1.y*x1.y + q1.z*x1.z + q1.w*x1.w;
            #pragma unroll
            for (int off = 32; off; off >>= 1) s += __shfl_down(s, off, 64);
            if (lane == 0) out_resp[((size_t)r_ * Bd + b_) * Hd + c] = tanh_fast(s);
        }
    }
}

extern "C" void kernel_launch(void* const* d_in, const int* in_sizes, int n_in,
                              void* d_out, int out_size, void* d_ws, size_t ws_size,
                              hipStream_t stream) {
    const float* ctx    = (const float*)d_in[0];  // (P,B,H)
    const float* resp   = (const float*)d_in[1];  // (R,W,B,H)
    const float* hidden = (const float*)d_in[2];  // (R,B,H)
    const float* Wc     = (const float*)d_in[3];
    const float* Wt     = (const float*)d_in[4];
    const float* Wa     = (const float*)d_in[5];
    const float* Walpha = (const float*)d_in[6];  // (H,1)
    const float* lin_w  = (const float*)d_in[7];
    const float* lin_p  = (const float*)d_in[8];
    const float* lin_x  = (const float*)d_in[9];

    float* out = (float*)d_out;
    float* resp_c_out = out;                       // R*B*H = 131072
    float* alpha_out  = out + Rd * Bd * Hd;        // R*W*B*P = 524288

    float* ws   = (float*)d_ws;
    float* WAc  = ws;                              //   524288 floats (512x1024)
    float* Wctx = ws + 524288;                     //  1048576
    float* rwb  = ws + 1572864;                    //  8388608 (64*256*512)
    unsigned* bar = (unsigned*)(ws + 9961472);     //  2 u32 (just past rwb)
    // scratch aliased into WAc: WA is fully consumed into LDS before the
    // first grid barrier, and w_glob/atten_g are first written only after it.
    float* w_glob  = WAc;                          //  262144 floats (256x1024)
    float* atten_g = WAc + 262144;                 //  131072 floats (256x512)

    dim3 g16(16, 16);
    k_prep_wa<<<g16, 256, 0, stream>>>(Wa, lin_w, WAc);
    k_wctx<<<128, 256, 0, stream>>>(ctx, Wc, Wctx);
    k_rw<<<1024, 256, 0, stream>>>(resp, Wt, rwb);
    hipMemsetAsync(bar, 0, 2 * sizeof(unsigned), stream);

    static bool s_attr = false;
    if (!s_attr) {
        hipFuncSetAttribute((const void*)k_scan,
                            hipFuncAttributeMaxDynamicSharedMemorySize, 98816);
        s_attr = true;
    }
    void* args[] = {
        (void*)&ctx, (void*)&rwb, (void*)&WAc, (void*)&Wctx, (void*)&Walpha,
        (void*)&hidden, (void*)&lin_p, (void*)&lin_x,
        (void*)&resp_c_out, (void*)&alpha_out,
        (void*)&w_glob, (void*)&atten_g, (void*)&bar
    };
    hipLaunchCooperativeKernel((const void*)k_scan, dim3(NBLK), dim3(512),
                               args, 98816, stream);
}

// Round 3
// 2089.376 us; speedup vs baseline: 2.2299x; 2.2299x over previous
//
#include <hip/hip_runtime.h>
#include <math.h>

#define Hd 512
#define Bd 64
#define Pd 32
#define Rd 4
#define Wd 64

__device__ __forceinline__ float tanh_fast(float x) {
    float e = __expf(x + x);
    return 1.f - __fdividef(2.f, 1.f + e);
}

// ---------------- build WA = [W_a | lin_w^T]  (512 x 1024) ----------------
__global__ void k_prep_wa(const float* __restrict__ Wa, const float* __restrict__ lin_w,
                          float* __restrict__ WAc) {
    __shared__ float tile[32][33];
    int bx = blockIdx.x, by = blockIdx.y;
    int lane = threadIdx.x & 31, ty = threadIdx.x >> 5;
    for (int k = 0; k < 32; k += 8) {
        int y = by * 32 + ty + k;
        WAc[(size_t)y * 1024 + bx * 32 + lane] = Wa[(size_t)y * Hd + bx * 32 + lane];
    }
    int x = bx * 32 + lane;
    for (int k = 0; k < 32; k += 8) {
        int y = by * 32 + ty + k;
        tile[ty + k][lane] = lin_w[(size_t)y * Hd + x];
    }
    __syncthreads();
    int xo = by * 32 + lane;
    for (int k = 0; k < 32; k += 8) {
        int yo = bx * 32 + ty + k;
        WAc[(size_t)yo * 1024 + 512 + xo] = tile[lane][ty + k];
    }
}

// ---------------- Wctx[b,p,k] = sum_h ctx[b,p,h] * Wc[h,k] ----------------
__global__ void k_wctx(const float* __restrict__ ctx_pbh, const float* __restrict__ Wc,
                       float* __restrict__ Wctx) {
    __shared__ float As[16][Hd];
    int r0 = blockIdx.x * 16;
    int tid = threadIdx.x;
    for (int rr = 0; rr < 16; ++rr) {
        int bp = r0 + rr;
        int b = bp >> 5, p = bp & 31;
        const float* src = ctx_pbh + ((size_t)p * Bd + b) * Hd;
        for (int h = tid; h < Hd; h += 256) As[rr][h] = src[h];
    }
    __syncthreads();
    int c0 = tid, c1 = tid + 256;
    float acc0[16], acc1[16];
    #pragma unroll
    for (int rr = 0; rr < 16; ++rr) { acc0[rr] = 0.f; acc1[rr] = 0.f; }
    for (int h = 0; h < Hd; ++h) {
        float w0 = Wc[(size_t)h * Hd + c0], w1 = Wc[(size_t)h * Hd + c1];
        #pragma unroll
        for (int rr = 0; rr < 16; ++rr) {
            float a = As[rr][h];
            acc0[rr] += a * w0;
            acc1[rr] += a * w1;
        }
    }
    for (int rr = 0; rr < 16; ++rr) {
        Wctx[(size_t)(r0 + rr) * Hd + c0] = acc0[rr];
        Wctx[(size_t)(r0 + rr) * Hd + c1] = acc1[rr];
    }
}

// ---------------- rw[t*256+row][k] = sum_h resp[r,t,b,h] * Wt[h,k] ----------------
__global__ __launch_bounds__(256) void k_rw(const float* __restrict__ resp,
                                            const float* __restrict__ Wt,
                                            float* __restrict__ rw) {
    __shared__ float As[16][Hd];
    int gr0 = blockIdx.x * 16;
    int tid = threadIdx.x;
    for (int rr = 0; rr < 16; ++rr) {
        int gr = gr0 + rr;
        int t = gr >> 8, row = gr & 255;
        int r = row >> 6, bb = row & 63;
        const float* src = resp + (((size_t)(r * Wd + t)) * Bd + bb) * Hd;
        for (int h = tid; h < Hd; h += 256) As[rr][h] = src[h];
    }
    __syncthreads();
    int c0 = tid, c1 = tid + 256;
    float acc0[16], acc1[16];
    #pragma unroll
    for (int rr = 0; rr < 16; ++rr) { acc0[rr] = 0.f; acc1[rr] = 0.f; }
    for (int h = 0; h < Hd; ++h) {
        float w0 = Wt[(size_t)h * Hd + c0], w1 = Wt[(size_t)h * Hd + c1];
        #pragma unroll
        for (int rr = 0; rr < 16; ++rr) {
            float a = As[rr][h];
            acc0[rr] += a * w0;
            acc1[rr] += a * w1;
        }
    }
    for (int rr = 0; rr < 16; ++rr) {
        rw[(size_t)(gr0 + rr) * Hd + c0] = acc0[rr];
        rw[(size_t)(gr0 + rr) * Hd + c1] = acc1[rr];
    }
}

// ---------------- persistent scan: 64 blocks (one per b), 1024 threads ----------------
// LDS-resident ctx[b] (64 KB) for the whole scan; phase A = 4-way split-K GEMM
// with float4 WA loads; softmax fused into the atten-update (4 barriers/step).
__global__ __launch_bounds__(1024, 4) void k_scan(
    const float* __restrict__ ctx,      // (P,B,H)
    const float* __restrict__ rw,       // (W*256, H)
    const float* __restrict__ WAc,      // (H, 1024)
    const float* __restrict__ Wctx,     // (B*P, H)
    const float* __restrict__ walpha,   // (H)
    const float* __restrict__ hidden,   // (R,B,H)
    const float* __restrict__ lin_p,    // (H,H) row-major, row = out col
    const float* __restrict__ lin_x,    // (H,H)
    float* __restrict__ out_resp,       // (R,B,H)
    float* __restrict__ out_alpha)      // (R,W,B,P)
{
    extern __shared__ float dynS[];
    float* sCtx   = dynS;                 // [32][512]   64 KB (persistent)
    float* sPart  = dynS + 16384;         // [4][4][1024] 64 KB (split-K partials / hidden in epilogue)
    float* sAtten = dynS + 32768;         // [4][512]     8 KB
    float* sW     = dynS + 34816;         // [4][1024]   16 KB
    __shared__ float sWal[Hd];            //  2 KB
    __shared__ float scS[Rd * Pd];        //  512 B

    const int b = blockIdx.x;
    const int tid = threadIdx.x;

    // ---- preamble: ctx[b] + walpha -> LDS, zero atten ----
    for (int i = tid; i < 4096; i += 1024) {            // 16384 floats as float4
        int p = i >> 7, h4 = (i & 127) << 2;
        *(float4*)&sCtx[(p << 9) + h4] =
            *(const float4*)&ctx[((size_t)(p * Bd + b)) * Hd + h4];
    }
    if (tid < Hd) sWal[tid] = walpha[tid];
    for (int i = tid; i < Rd * Hd; i += 1024) sAtten[i] = 0.f;
    __syncthreads();

    // ---- identities ----
    const int qid = tid >> 8;                 // h-quarter 0..3
    const int hq  = qid << 7;                 // h base of quarter
    const int cq  = (tid & 255) << 2;         // col quad 0..1020
    const float* __restrict__ wabase = WAc + ((size_t)hq << 10) + cq;

    const int rowR = tid >> 8;                // reduce: row 0..3
    const int ccR  = (tid & 255) << 2;        // reduce: col quad

    const int pB  = tid >> 5;                 // score: p 0..31
    const int hcB = tid & 31;
    const float* __restrict__ wrow = Wctx + ((size_t)(b * Pd + pB)) * Hd;

    const int rD = tid >> 8;                  // update: row 0..3
    const int hD = (tid & 255) << 1;          // update: h pair

    for (int t = 0; t < Wd; ++t) {
        // prefetch rw slice (consumed in the reduce; latency hides under A)
        float4 rv = make_float4(0.f, 0.f, 0.f, 0.f);
        if (ccR < Hd)
            rv = *(const float4*)&rw[((size_t)t * 256 + rowR * 64 + b) * Hd + ccR];

        // ---- A: partial GEMM  [w | lw](cq..cq+3) over h in [hq, hq+128) ----
        if (t > 0) {
            float4 acc0 = make_float4(0.f,0.f,0.f,0.f);
            float4 acc1 = acc0, acc2 = acc0, acc3 = acc0;
            #pragma unroll 2
            for (int it = 0; it < 32; ++it) {
                const float* q = wabase + ((size_t)it << 12);
                float4 w0 = *(const float4*)(q);
                float4 w1 = *(const float4*)(q + 1024);
                float4 w2 = *(const float4*)(q + 2048);
                float4 w3 = *(const float4*)(q + 3072);
                const int h = hq + (it << 2);
                float4 a0 = *(const float4*)&sAtten[h];
                float4 a1 = *(const float4*)&sAtten[512 + h];
                float4 a2 = *(const float4*)&sAtten[1024 + h];
                float4 a3 = *(const float4*)&sAtten[1536 + h];
                acc0.x += a0.x*w0.x + a0.y*w1.x + a0.z*w2.x + a0.w*w3.x;
                acc0.y += a0.x*w0.y + a0.y*w1.y + a0.z*w2.y + a0.w*w3.y;
                acc0.z += a0.x*w0.z + a0.y*w1.z + a0.z*w2.z + a0.w*w3.z;
                acc0.w += a0.x*w0.w + a0.y*w1.w + a0.z*w2.w + a0.w*w3.w;
                acc1.x += a1.x*w0.x + a1.y*w1.x + a1.z*w2.x + a1.w*w3.x;
                acc1.y += a1.x*w0.y + a1.y*w1.y + a1.z*w2.y + a1.w*w3.y;
                acc1.z += a1.x*w0.z + a1.y*w1.z + a1.z*w2.z + a1.w*w3.z;
                acc1.w += a1.x*w0.w + a1.y*w1.w + a1.z*w2.w + a1.w*w3.w;
                acc2.x += a2.x*w0.x + a2.y*w1.x + a2.z*w2.x + a2.w*w3.x;
                acc2.y += a2.x*w0.y + a2.y*w1.y + a2.z*w2.y + a2.w*w3.y;
                acc2.z += a2.x*w0.z + a2.y*w1.z + a2.z*w2.z + a2.w*w3.z;
                acc2.w += a2.x*w0.w + a2.y*w1.w + a2.z*w2.w + a2.w*w3.w;
                acc3.x += a3.x*w0.x + a3.y*w1.x + a3.z*w2.x + a3.w*w3.x;
                acc3.y += a3.x*w0.y + a3.y*w1.y + a3.z*w2.y + a3.w*w3.y;
                acc3.z += a3.x*w0.z + a3.y*w1.z + a3.z*w2.z + a3.w*w3.z;
                acc3.w += a3.x*w0.w + a3.y*w1.w + a3.z*w2.w + a3.w*w3.w;
            }
            *(float4*)&sPart[((qid << 2) + 0) * 1024 + cq] = acc0;
            *(float4*)&sPart[((qid << 2) + 1) * 1024 + cq] = acc1;
            *(float4*)&sPart[((qid << 2) + 2) * 1024 + cq] = acc2;
            *(float4*)&sPart[((qid << 2) + 3) * 1024 + cq] = acc3;
            __syncthreads();
        }

        // ---- reduce split-K partials + rw -> sW ----
        {
            float4 s = make_float4(0.f, 0.f, 0.f, 0.f);
            if (t > 0) {
                #pragma unroll
                for (int q = 0; q < 4; ++q) {
                    float4 p = *(const float4*)&sPart[((q << 2) + rowR) * 1024 + ccR];
                    s.x += p.x; s.y += p.y; s.z += p.z; s.w += p.w;
                }
            }
            if (ccR < Hd) { s.x += rv.x; s.y += rv.y; s.z += rv.z; s.w += rv.w; }
            *(float4*)&sW[(rowR << 10) + ccR] = s;
        }
        __syncthreads();

        // ---- B: score[r][p] = sum_h tanh(Wctx[b,p,h]+w[r,h])*walpha[h] ----
        {
            float sc0 = 0.f, sc1 = 0.f, sc2 = 0.f, sc3 = 0.f;
            #pragma unroll
            for (int k = 0; k < 4; ++k) {
                int h4 = (k << 7) + (hcB << 2);
                float4 wc  = *(const float4*)&wrow[h4];
                float4 wal = *(const float4*)&sWal[h4];
                float4 v0 = *(const float4*)&sW[h4];
                float4 v1 = *(const float4*)&sW[1024 + h4];
                float4 v2 = *(const float4*)&sW[2048 + h4];
                float4 v3 = *(const float4*)&sW[3072 + h4];
                sc0 += tanh_fast(wc.x+v0.x)*wal.x + tanh_fast(wc.y+v0.y)*wal.y
                     + tanh_fast(wc.z+v0.z)*wal.z + tanh_fast(wc.w+v0.w)*wal.w;
                sc1 += tanh_fast(wc.x+v1.x)*wal.x + tanh_fast(wc.y+v1.y)*wal.y
                     + tanh_fast(wc.z+v1.z)*wal.z + tanh_fast(wc.w+v1.w)*wal.w;
                sc2 += tanh_fast(wc.x+v2.x)*wal.x + tanh_fast(wc.y+v2.y)*wal.y
                     + tanh_fast(wc.z+v2.z)*wal.z + tanh_fast(wc.w+v2.w)*wal.w;
                sc3 += tanh_fast(wc.x+v3.x)*wal.x + tanh_fast(wc.y+v3.y)*wal.y
                     + tanh_fast(wc.z+v3.z)*wal.z + tanh_fast(wc.w+v3.w)*wal.w;
            }
            #pragma unroll
            for (int off = 16; off; off >>= 1) {
                sc0 += __shfl_down(sc0, off, 32);
                sc1 += __shfl_down(sc1, off, 32);
                sc2 += __shfl_down(sc2, off, 32);
                sc3 += __shfl_down(sc3, off, 32);
            }
            if (hcB == 0) { scS[pB] = sc0; scS[32 + pB] = sc1;
                            scS[64 + pB] = sc2; scS[96 + pB] = sc3; }
        }
        __syncthreads();

        // ---- C (out_alpha writer, threads 0..127) ----
        if (tid < 128) {
            int r = tid >> 5, pp = tid & 31;
            float s = scS[(r << 5) + pp];
            float m = s;
            #pragma unroll
            for (int off = 16; off; off >>= 1) m = fmaxf(m, __shfl_xor(m, off, 32));
            float e = __expf(s - m);
            float sum = e;
            #pragma unroll
            for (int off = 16; off; off >>= 1) sum += __shfl_xor(sum, off, 32);
            out_alpha[(((size_t)r * Wd + t) * Bd + b) * Pd + pp] = e * __fdividef(1.f, sum);
        }

        // ---- C'+D: redundant in-register softmax, then atten update ----
        {
            float sv[Pd];
            #pragma unroll
            for (int p = 0; p < Pd; ++p) sv[p] = scS[(rD << 5) + p];
            float m = sv[0];
            #pragma unroll
            for (int p = 1; p < Pd; ++p) m = fmaxf(m, sv[p]);
            float sum = 0.f;
            #pragma unroll
            for (int p = 0; p < Pd; ++p) { sv[p] = __expf(sv[p] - m); sum += sv[p]; }
            float inv = __fdividef(1.f, sum);

            float a0 = 0.f, a1 = 0.f;
            #pragma unroll
            for (int p = 0; p < Pd; ++p) {
                float al = sv[p] * inv;
                float2 cv = *(const float2*)&sCtx[(p << 9) + hD];
                a0 += al * cv.x;
                a1 += al * cv.y;
            }
            a0 += tanh_fast(sW[(rD << 10) + Hd + hD]);
            a1 += tanh_fast(sW[(rD << 10) + Hd + hD + 1]);
            *(float2*)&sAtten[(rD << 9) + hD] = make_float2(a0, a1);
        }
        __syncthreads();
    }

    // ---- epilogue: resp_c = tanh(atten@lin_p^T + hidden@lin_x^T) ----
    for (int i = tid; i < Rd * Hd; i += 1024) {
        int r = i >> 9, h = i & 511;
        sPart[i] = hidden[((size_t)r * Bd + b) * Hd + h];
    }
    __syncthreads();
    {
        const int r2 = tid >> 9;               // 0..1 -> rows {2r2, 2r2+1}
        const int c  = tid & 511;
        const int ra = r2 * 2, rb = ra + 1;
        const float* __restrict__ lp = lin_p + (size_t)c * Hd;
        const float* __restrict__ lx = lin_x + (size_t)c * Hd;
        float fa = 0.f, fb = 0.f;
        #pragma unroll 2
        for (int h = 0; h < Hd; h += 4) {
            float4 lpv = *(const float4*)(lp + h);
            float4 lxv = *(const float4*)(lx + h);
            float4 aa  = *(const float4*)&sAtten[(ra << 9) + h];
            float4 ab  = *(const float4*)&sAtten[(rb << 9) + h];
            float4 ha  = *(const float4*)&sPart[(ra << 9) + h];
            float4 hb  = *(const float4*)&sPart[(rb << 9) + h];
            fa += aa.x*lpv.x + aa.y*lpv.y + aa.z*lpv.z + aa.w*lpv.w
                + ha.x*lxv.x + ha.y*lxv.y + ha.z*lxv.z + ha.w*lxv.w;
            fb += ab.x*lpv.x + ab.y*lpv.y + ab.z*lpv.z + ab.w*lpv.w
                + hb.x*lxv.x + hb.y*lxv.y + hb.z*lxv.z + hb.w*lxv.w;
        }
        out_resp[((size_t)ra * Bd + b) * Hd + c] = tanh_fast(fa);
        out_resp[((size_t)rb * Bd + b) * Hd + c] = tanh_fast(fb);
    }
}

extern "C" void kernel_launch(void* const* d_in, const int* in_sizes, int n_in,
                              void* d_out, int out_size, void* d_ws, size_t ws_size,
                              hipStream_t stream) {
    const float* ctx    = (const float*)d_in[0];  // (P,B,H)
    const float* resp   = (const float*)d_in[1];  // (R,W,B,H)
    const float* hidden = (const float*)d_in[2];  // (R,B,H)
    const float* Wc     = (const float*)d_in[3];
    const float* Wt     = (const float*)d_in[4];
    const float* Wa     = (const float*)d_in[5];
    const float* Walpha = (const float*)d_in[6];  // (H,1)
    const float* lin_w  = (const float*)d_in[7];
    const float* lin_p  = (const float*)d_in[8];
    const float* lin_x  = (const float*)d_in[9];

    float* out = (float*)d_out;
    float* resp_c_out = out;                       // R*B*H = 131072
    float* alpha_out  = out + Rd * Bd * Hd;        // R*W*B*P = 524288

    float* ws   = (float*)d_ws;
    float* WAc  = ws;                              //   524288 floats (512x1024)
    float* Wctx = ws + 524288;                     //  1048576
    float* rwb  = ws + 1572864;                    //  8388608 (64*256*512)

    dim3 g16(16, 16);
    k_prep_wa<<<g16, 256, 0, stream>>>(Wa, lin_w, WAc);
    k_wctx<<<128, 256, 0, stream>>>(ctx, Wc, Wctx);
    k_rw<<<1024, 256, 0, stream>>>(resp, Wt, rwb);

    const int dyn_lds = 155648;                    // 38912 floats
    static bool s_attr = false;
    if (!s_attr) {
        hipFuncSetAttribute((const void*)k_scan,
                            hipFuncAttributeMaxDynamicSharedMemorySize, dyn_lds);
        s_attr = true;
    }
    k_scan<<<64, 1024, dyn_lds, stream>>>(ctx, rwb, WAc, Wctx, Walpha, hidden,
                                          lin_p, lin_x, resp_c_out, alpha_out);
}

// Round 4
// 1734.209 us; speedup vs baseline: 2.6866x; 1.2048x over previous
//
#include <hip/hip_runtime.h>
#include <math.h>

#define Hd 512
#define Bd 64
#define Pd 32
#define Rd 4
#define Wd 64

typedef _Float16 h2v __attribute__((ext_vector_type(2)));

__device__ __forceinline__ float tanh_fast(float x) {
    float e = __expf(x + x);
    return 1.f - __fdividef(2.f, 1.f + e);
}

__device__ __forceinline__ float d2(unsigned a, unsigned b, float c) {
    return __builtin_amdgcn_fdot2(__builtin_bit_cast(h2v, a),
                                  __builtin_bit_cast(h2v, b), c, false);
}

// ---------------- build WA = [W_a | lin_w^T]  (512 x 1024), fp32 ----------------
__global__ void k_prep_wa(const float* __restrict__ Wa, const float* __restrict__ lin_w,
                          float* __restrict__ WAc) {
    __shared__ float tile[32][33];
    int bx = blockIdx.x, by = blockIdx.y;
    int lane = threadIdx.x & 31, ty = threadIdx.x >> 5;
    for (int k = 0; k < 32; k += 8) {
        int y = by * 32 + ty + k;
        WAc[(size_t)y * 1024 + bx * 32 + lane] = Wa[(size_t)y * Hd + bx * 32 + lane];
    }
    int x = bx * 32 + lane;
    for (int k = 0; k < 32; k += 8) {
        int y = by * 32 + ty + k;
        tile[ty + k][lane] = lin_w[(size_t)y * Hd + x];
    }
    __syncthreads();
    int xo = by * 32 + lane;
    for (int k = 0; k < 32; k += 8) {
        int yo = bx * 32 + ty + k;
        WAc[(size_t)yo * 1024 + 512 + xo] = tile[lane][ty + k];
    }
}

// ---------------- pack WA into half2 pairs along h: WAp[h/2][c] ----------------
__global__ __launch_bounds__(256) void k_pack(const float* __restrict__ WAc,
                                              unsigned* __restrict__ WAp) {
    int idx = blockIdx.x * 256 + threadIdx.x;     // h2*1024 + c
    int h2 = idx >> 10, c = idx & 1023;
    h2v p;
    p.x = (_Float16)WAc[((size_t)(2 * h2)) * 1024 + c];
    p.y = (_Float16)WAc[((size_t)(2 * h2 + 1)) * 1024 + c];
    WAp[idx] = __builtin_bit_cast(unsigned, p);
}

// ---------------- Wctx[b,p,k] = sum_h ctx[b,p,h] * Wc[h,k] ----------------
__global__ void k_wctx(const float* __restrict__ ctx_pbh, const float* __restrict__ Wc,
                       float* __restrict__ Wctx) {
    __shared__ float As[16][Hd];
    int r0 = blockIdx.x * 16;
    int tid = threadIdx.x;
    for (int rr = 0; rr < 16; ++rr) {
        int bp = r0 + rr;
        int b = bp >> 5, p = bp & 31;
        const float* src = ctx_pbh + ((size_t)p * Bd + b) * Hd;
        for (int h = tid; h < Hd; h += 256) As[rr][h] = src[h];
    }
    __syncthreads();
    int c0 = tid, c1 = tid + 256;
    float acc0[16], acc1[16];
    #pragma unroll
    for (int rr = 0; rr < 16; ++rr) { acc0[rr] = 0.f; acc1[rr] = 0.f; }
    for (int h = 0; h < Hd; ++h) {
        float w0 = Wc[(size_t)h * Hd + c0], w1 = Wc[(size_t)h * Hd + c1];
        #pragma unroll
        for (int rr = 0; rr < 16; ++rr) {
            float a = As[rr][h];
            acc0[rr] += a * w0;
            acc1[rr] += a * w1;
        }
    }
    for (int rr = 0; rr < 16; ++rr) {
        Wctx[(size_t)(r0 + rr) * Hd + c0] = acc0[rr];
        Wctx[(size_t)(r0 + rr) * Hd + c1] = acc1[rr];
    }
}

// ---------------- rwh[t*256+row][k] = fp16( sum_h resp[r,t,b,h] * Wt[h,k] ) ----------------
__global__ __launch_bounds__(256) void k_rw(const float* __restrict__ resp,
                                            const float* __restrict__ Wt,
                                            unsigned short* __restrict__ rwh) {
    __shared__ float As[16][Hd];
    int gr0 = blockIdx.x * 16;
    int tid = threadIdx.x;
    for (int rr = 0; rr < 16; ++rr) {
        int gr = gr0 + rr;
        int t = gr >> 8, row = gr & 255;
        int r = row >> 6, bb = row & 63;
        const float* src = resp + (((size_t)(r * Wd + t)) * Bd + bb) * Hd;
        for (int h = tid; h < Hd; h += 256) As[rr][h] = src[h];
    }
    __syncthreads();
    int c0 = tid, c1 = tid + 256;
    float acc0[16], acc1[16];
    #pragma unroll
    for (int rr = 0; rr < 16; ++rr) { acc0[rr] = 0.f; acc1[rr] = 0.f; }
    for (int h = 0; h < Hd; ++h) {
        float w0 = Wt[(size_t)h * Hd + c0], w1 = Wt[(size_t)h * Hd + c1];
        #pragma unroll
        for (int rr = 0; rr < 16; ++rr) {
            float a = As[rr][h];
            acc0[rr] += a * w0;
            acc1[rr] += a * w1;
        }
    }
    for (int rr = 0; rr < 16; ++rr) {
        rwh[(size_t)(gr0 + rr) * Hd + c0] =
            __builtin_bit_cast(unsigned short, (_Float16)acc0[rr]);
        rwh[(size_t)(gr0 + rr) * Hd + c1] =
            __builtin_bit_cast(unsigned short, (_Float16)acc1[rr]);
    }
}

// ---------------- persistent scan: 64 blocks (one per b), 1024 threads ----------------
// fp16 datapath for phase A: WA packed half2 (global stream 1 MB/step),
// atten mirrored as half2 in LDS, v_dot2_f32_f16 MACs with fp32 accumulation.
__global__ __launch_bounds__(1024, 4) void k_scan(
    const float* __restrict__ ctx,      // (P,B,H)
    const unsigned short* __restrict__ rwh, // (W*256, H) fp16
    const unsigned* __restrict__ WAp,   // (H/2, 1024) half2 pairs along h
    const float* __restrict__ Wctx,     // (B*P, H)
    const float* __restrict__ walpha,   // (H)
    const float* __restrict__ hidden,   // (R,B,H)
    const float* __restrict__ lin_p,    // (H,H) row-major, row = out col
    const float* __restrict__ lin_x,    // (H,H)
    float* __restrict__ out_resp,       // (R,B,H)
    float* __restrict__ out_alpha)      // (R,W,B,P)
{
    extern __shared__ float dynS[];
    float* sCtx   = dynS;                 // [32][512]    64 KB (persistent)
    float* sPart  = dynS + 16384;         // [4][4][1024] 64 KB (split-K partials / hidden in epilogue)
    float* sAtten = dynS + 32768;         // [4][512]      8 KB (fp32, epilogue)
    float* sW     = dynS + 34816;         // [4][1024]    16 KB
    unsigned* sAttenH = (unsigned*)(dynS + 38912); // [4][256] half2 4 KB
    __shared__ float sWal[Hd];            //  2 KB
    __shared__ float scS[Rd * Pd];        //  512 B

    const int b = blockIdx.x;
    const int tid = threadIdx.x;

    // ---- preamble: ctx[b] + walpha -> LDS, zero atten (both copies) ----
    for (int i = tid; i < 4096; i += 1024) {
        int p = i >> 7, h4 = (i & 127) << 2;
        *(float4*)&sCtx[(p << 9) + h4] =
            *(const float4*)&ctx[((size_t)(p * Bd + b)) * Hd + h4];
    }
    if (tid < Hd) sWal[tid] = walpha[tid];
    for (int i = tid; i < Rd * Hd; i += 1024) sAtten[i] = 0.f;
    if (tid < 1024) sAttenH[tid] = 0u;
    __syncthreads();

    // ---- identities ----
    const int qid = tid >> 8;                 // h-quarter 0..3
    const int cq  = (tid & 255) << 2;         // col quad 0..1020
    const unsigned* __restrict__ wap = WAp + (((size_t)qid << 6) << 10) + cq; // h2 base = qid*64
    const unsigned* __restrict__ ah  = sAttenH + (qid << 6);

    const int rowR = tid >> 8;                // reduce: row 0..3
    const int ccR  = (tid & 255) << 2;        // reduce: col quad

    const int pB  = tid >> 5;                 // score: p 0..31
    const int hcB = tid & 31;
    const float* __restrict__ wrow = Wctx + ((size_t)(b * Pd + pB)) * Hd;

    const int rD = tid >> 8;                  // update: row 0..3
    const int hD = (tid & 255) << 1;          // update: h pair

    for (int t = 0; t < Wd; ++t) {
        // prefetch rw slice fp16 (consumed in the reduce)
        uint2 rvu = make_uint2(0u, 0u);
        if (ccR < Hd)
            rvu = *(const uint2*)((const unsigned*)rwh
                   + (((size_t)t * 256 + rowR * 64 + b) << 8) + (ccR >> 1));

        // ---- A: partial GEMM  [w | lw](cq..cq+3) over h in [hq, hq+128), fp16 dot2 ----
        if (t > 0) {
            float4 acc0 = make_float4(0.f,0.f,0.f,0.f);
            float4 acc1 = acc0, acc2 = acc0, acc3 = acc0;
            #pragma unroll 2
            for (int jq = 0; jq < 16; ++jq) {
                const unsigned* wq = wap + (((size_t)jq << 2) << 10);
                uint4 w0 = *(const uint4*)(wq);
                uint4 w1 = *(const uint4*)(wq + 1024);
                uint4 w2 = *(const uint4*)(wq + 2048);
                uint4 w3 = *(const uint4*)(wq + 3072);
                uint4 a0 = *(const uint4*)(ah + (jq << 2));
                uint4 a1 = *(const uint4*)(ah + 256 + (jq << 2));
                uint4 a2 = *(const uint4*)(ah + 512 + (jq << 2));
                uint4 a3 = *(const uint4*)(ah + 768 + (jq << 2));
                #define ROW(accr, ar) \
                    accr.x = d2(ar.x, w0.x, accr.x); accr.y = d2(ar.x, w0.y, accr.y); \
                    accr.z = d2(ar.x, w0.z, accr.z); accr.w = d2(ar.x, w0.w, accr.w); \
                    accr.x = d2(ar.y, w1.x, accr.x); accr.y = d2(ar.y, w1.y, accr.y); \
                    accr.z = d2(ar.y, w1.z, accr.z); accr.w = d2(ar.y, w1.w, accr.w); \
                    accr.x = d2(ar.z, w2.x, accr.x); accr.y = d2(ar.z, w2.y, accr.y); \
                    accr.z = d2(ar.z, w2.z, accr.z); accr.w = d2(ar.z, w2.w, accr.w); \
                    accr.x = d2(ar.w, w3.x, accr.x); accr.y = d2(ar.w, w3.y, accr.y); \
                    accr.z = d2(ar.w, w3.z, accr.z); accr.w = d2(ar.w, w3.w, accr.w);
                ROW(acc0, a0) ROW(acc1, a1) ROW(acc2, a2) ROW(acc3, a3)
                #undef ROW
            }
            *(float4*)&sPart[((qid << 2) + 0) * 1024 + cq] = acc0;
            *(float4*)&sPart[((qid << 2) + 1) * 1024 + cq] = acc1;
            *(float4*)&sPart[((qid << 2) + 2) * 1024 + cq] = acc2;
            *(float4*)&sPart[((qid << 2) + 3) * 1024 + cq] = acc3;
            __syncthreads();
        }

        // ---- reduce split-K partials + rw -> sW ----
        {
            float4 s = make_float4(0.f, 0.f, 0.f, 0.f);
            if (t > 0) {
                #pragma unroll
                for (int q = 0; q < 4; ++q) {
                    float4 p = *(const float4*)&sPart[((q << 2) + rowR) * 1024 + ccR];
                    s.x += p.x; s.y += p.y; s.z += p.z; s.w += p.w;
                }
            }
            if (ccR < Hd) {
                h2v p0 = __builtin_bit_cast(h2v, rvu.x);
                h2v p1 = __builtin_bit_cast(h2v, rvu.y);
                s.x += (float)p0.x; s.y += (float)p0.y;
                s.z += (float)p1.x; s.w += (float)p1.y;
            }
            *(float4*)&sW[(rowR << 10) + ccR] = s;
        }
        __syncthreads();

        // ---- B: score[r][p] = sum_h tanh(Wctx[b,p,h]+w[r,h])*walpha[h] ----
        {
            float sc0 = 0.f, sc1 = 0.f, sc2 = 0.f, sc3 = 0.f;
            #pragma unroll
            for (int k = 0; k < 4; ++k) {
                int h4 = (k << 7) + (hcB << 2);
                float4 wc  = *(const float4*)&wrow[h4];
                float4 wal = *(const float4*)&sWal[h4];
                float4 v0 = *(const float4*)&sW[h4];
                float4 v1 = *(const float4*)&sW[1024 + h4];
                float4 v2 = *(const float4*)&sW[2048 + h4];
                float4 v3 = *(const float4*)&sW[3072 + h4];
                sc0 += tanh_fast(wc.x+v0.x)*wal.x + tanh_fast(wc.y+v0.y)*wal.y
                     + tanh_fast(wc.z+v0.z)*wal.z + tanh_fast(wc.w+v0.w)*wal.w;
                sc1 += tanh_fast(wc.x+v1.x)*wal.x + tanh_fast(wc.y+v1.y)*wal.y
                     + tanh_fast(wc.z+v1.z)*wal.z + tanh_fast(wc.w+v1.w)*wal.w;
                sc2 += tanh_fast(wc.x+v2.x)*wal.x + tanh_fast(wc.y+v2.y)*wal.y
                     + tanh_fast(wc.z+v2.z)*wal.z + tanh_fast(wc.w+v2.w)*wal.w;
                sc3 += tanh_fast(wc.x+v3.x)*wal.x + tanh_fast(wc.y+v3.y)*wal.y
                     + tanh_fast(wc.z+v3.z)*wal.z + tanh_fast(wc.w+v3.w)*wal.w;
            }
            #pragma unroll
            for (int off = 16; off; off >>= 1) {
                sc0 += __shfl_down(sc0, off, 32);
                sc1 += __shfl_down(sc1, off, 32);
                sc2 += __shfl_down(sc2, off, 32);
                sc3 += __shfl_down(sc3, off, 32);
            }
            if (hcB == 0) { scS[pB] = sc0; scS[32 + pB] = sc1;
                            scS[64 + pB] = sc2; scS[96 + pB] = sc3; }
        }
        __syncthreads();

        // ---- C (out_alpha writer, threads 0..127) ----
        if (tid < 128) {
            int r = tid >> 5, pp = tid & 31;
            float s = scS[(r << 5) + pp];
            float m = s;
            #pragma unroll
            for (int off = 16; off; off >>= 1) m = fmaxf(m, __shfl_xor(m, off, 32));
            float e = __expf(s - m);
            float sum = e;
            #pragma unroll
            for (int off = 16; off; off >>= 1) sum += __shfl_xor(sum, off, 32);
            out_alpha[(((size_t)r * Wd + t) * Bd + b) * Pd + pp] = e * __fdividef(1.f, sum);
        }

        // ---- C'+D: redundant in-register softmax, then atten update ----
        {
            float sv[Pd];
            #pragma unroll
            for (int p = 0; p < Pd; ++p) sv[p] = scS[(rD << 5) + p];
            float m = sv[0];
            #pragma unroll
            for (int p = 1; p < Pd; ++p) m = fmaxf(m, sv[p]);
            float sum = 0.f;
            #pragma unroll
            for (int p = 0; p < Pd; ++p) { sv[p] = __expf(sv[p] - m); sum += sv[p]; }
            float inv = __fdividef(1.f, sum);

            float a0 = 0.f, a1 = 0.f;
            #pragma unroll
            for (int p = 0; p < Pd; ++p) {
                float al = sv[p] * inv;
                float2 cv = *(const float2*)&sCtx[(p << 9) + hD];
                a0 += al * cv.x;
                a1 += al * cv.y;
            }
            a0 += tanh_fast(sW[(rD << 10) + Hd + hD]);
            a1 += tanh_fast(sW[(rD << 10) + Hd + hD + 1]);
            *(float2*)&sAtten[(rD << 9) + hD] = make_float2(a0, a1);
            h2v ph; ph.x = (_Float16)a0; ph.y = (_Float16)a1;
            sAttenH[(rD << 8) + (hD >> 1)] = __builtin_bit_cast(unsigned, ph);
        }
        __syncthreads();
    }

    // ---- epilogue: resp_c = tanh(atten@lin_p^T + hidden@lin_x^T) ----
    for (int i = tid; i < Rd * Hd; i += 1024) {
        int r = i >> 9, h = i & 511;
        sPart[i] = hidden[((size_t)r * Bd + b) * Hd + h];
    }
    __syncthreads();
    {
        const int r2 = tid >> 9;               // 0..1 -> rows {2r2, 2r2+1}
        const int c  = tid & 511;
        const int ra = r2 * 2, rb = ra + 1;
        const float* __restrict__ lp = lin_p + (size_t)c * Hd;
        const float* __restrict__ lx = lin_x + (size_t)c * Hd;
        float fa = 0.f, fb = 0.f;
        #pragma unroll 2
        for (int h = 0; h < Hd; h += 4) {
            float4 lpv = *(const float4*)(lp + h);
            float4 lxv = *(const float4*)(lx + h);
            float4 aa  = *(const float4*)&sAtten[(ra << 9) + h];
            float4 ab  = *(const float4*)&sAtten[(rb << 9) + h];
            float4 ha  = *(const float4*)&sPart[(ra << 9) + h];
            float4 hb  = *(const float4*)&sPart[(rb << 9) + h];
            fa += aa.x*lpv.x + aa.y*lpv.y + aa.z*lpv.z + aa.w*lpv.w
                + ha.x*lxv.x + ha.y*lxv.y + ha.z*lxv.z + ha.w*lxv.w;
            fb += ab.x*lpv.x + ab.y*lpv.y + ab.z*lpv.z + ab.w*lpv.w
                + hb.x*lxv.x + hb.y*lxv.y + hb.z*lxv.z + hb.w*lxv.w;
        }
        out_resp[((size_t)ra * Bd + b) * Hd + c] = tanh_fast(fa);
        out_resp[((size_t)rb * Bd + b) * Hd + c] = tanh_fast(fb);
    }
}

extern "C" void kernel_launch(void* const* d_in, const int* in_sizes, int n_in,
                              void* d_out, int out_size, void* d_ws, size_t ws_size,
                              hipStream_t stream) {
    const float* ctx    = (const float*)d_in[0];  // (P,B,H)
    const float* resp   = (const float*)d_in[1];  // (R,W,B,H)
    const float* hidden = (const float*)d_in[2];  // (R,B,H)
    const float* Wc     = (const float*)d_in[3];
    const float* Wt     = (const float*)d_in[4];
    const float* Wa     = (const float*)d_in[5];
    const float* Walpha = (const float*)d_in[6];  // (H,1)
    const float* lin_w  = (const float*)d_in[7];
    const float* lin_p  = (const float*)d_in[8];
    const float* lin_x  = (const float*)d_in[9];

    float* out = (float*)d_out;
    float* resp_c_out = out;                       // R*B*H = 131072
    float* alpha_out  = out + Rd * Bd * Hd;        // R*W*B*P = 524288

    float* ws   = (float*)d_ws;
    float* WAc  = ws;                              //   524288 floats (512x1024 fp32)
    float* Wctx = ws + 524288;                     //  1048576 floats
    unsigned short* rwh = (unsigned short*)(ws + 1572864); // 8388608 ushorts (4194304 floats)
    unsigned* WAp = (unsigned*)(ws + 5767168);     //   262144 uints (256x1024 half2)
    // total 6029312 floats = 24.1 MB (under the proven 39.8 MB)

    dim3 g16(16, 16);
    k_prep_wa<<<g16, 256, 0, stream>>>(Wa, lin_w, WAc);
    k_pack<<<1024, 256, 0, stream>>>(WAc, WAp);
    k_wctx<<<128, 256, 0, stream>>>(ctx, Wc, Wctx);
    k_rw<<<1024, 256, 0, stream>>>(resp, Wt, rwh);

    const int dyn_lds = 159744;                    // 39936 floats
    static bool s_attr = false;
    if (!s_attr) {
        hipFuncSetAttribute((const void*)k_scan,
                            hipFuncAttributeMaxDynamicSharedMemorySize, dyn_lds);
        s_attr = true;
    }
    k_scan<<<64, 1024, dyn_lds, stream>>>(ctx, rwh, WAp, Wctx, Walpha, hidden,
                                          lin_p, lin_x, resp_c_out, alpha_out);
}

// Round 5
// 1114.328 us; speedup vs baseline: 4.1811x; 1.5563x over previous
//
#include <hip/hip_runtime.h>
#include <math.h>

#define Hd 512
#define Bd 64
#define Pd 32
#define Rd 4
#define Wd 64

typedef _Float16 h2v __attribute__((ext_vector_type(2)));

__device__ __forceinline__ float tanh_fast(float x) {
    float e = __expf(x + x);
    return 1.f - __fdividef(2.f, 1.f + e);
}

__device__ __forceinline__ float d2(unsigned a, unsigned b, float c) {
    return __builtin_amdgcn_fdot2(__builtin_bit_cast(h2v, a),
                                  __builtin_bit_cast(h2v, b), c, false);
}

// ---------------- build WA = [W_a | lin_w^T]  (512 x 1024), fp32 ----------------
__global__ void k_prep_wa(const float* __restrict__ Wa, const float* __restrict__ lin_w,
                          float* __restrict__ WAc) {
    __shared__ float tile[32][33];
    int bx = blockIdx.x, by = blockIdx.y;
    int lane = threadIdx.x & 31, ty = threadIdx.x >> 5;
    for (int k = 0; k < 32; k += 8) {
        int y = by * 32 + ty + k;
        WAc[(size_t)y * 1024 + bx * 32 + lane] = Wa[(size_t)y * Hd + bx * 32 + lane];
    }
    int x = bx * 32 + lane;
    for (int k = 0; k < 32; k += 8) {
        int y = by * 32 + ty + k;
        tile[ty + k][lane] = lin_w[(size_t)y * Hd + x];
    }
    __syncthreads();
    int xo = by * 32 + lane;
    for (int k = 0; k < 32; k += 8) {
        int yo = bx * 32 + ty + k;
        WAc[(size_t)yo * 1024 + 512 + xo] = tile[lane][ty + k];
    }
}

// ---------------- pack WA into half2 pairs along h: WAp[h/2][c] ----------------
__global__ __launch_bounds__(256) void k_pack(const float* __restrict__ WAc,
                                              unsigned* __restrict__ WAp) {
    int idx = blockIdx.x * 256 + threadIdx.x;     // h2*1024 + c
    int h2 = idx >> 10, c = idx & 1023;
    h2v p;
    p.x = (_Float16)WAc[((size_t)(2 * h2)) * 1024 + c];
    p.y = (_Float16)WAc[((size_t)(2 * h2 + 1)) * 1024 + c];
    WAp[idx] = __builtin_bit_cast(unsigned, p);
}

// ---------------- Wctx[b,p,k] = sum_h ctx[b,p,h] * Wc[h,k] ----------------
__global__ void k_wctx(const float* __restrict__ ctx_pbh, const float* __restrict__ Wc,
                       float* __restrict__ Wctx) {
    __shared__ float As[16][Hd];
    int r0 = blockIdx.x * 16;
    int tid = threadIdx.x;
    for (int rr = 0; rr < 16; ++rr) {
        int bp = r0 + rr;
        int b = bp >> 5, p = bp & 31;
        const float* src = ctx_pbh + ((size_t)p * Bd + b) * Hd;
        for (int h = tid; h < Hd; h += 256) As[rr][h] = src[h];
    }
    __syncthreads();
    int c0 = tid, c1 = tid + 256;
    float acc0[16], acc1[16];
    #pragma unroll
    for (int rr = 0; rr < 16; ++rr) { acc0[rr] = 0.f; acc1[rr] = 0.f; }
    for (int h = 0; h < Hd; ++h) {
        float w0 = Wc[(size_t)h * Hd + c0], w1 = Wc[(size_t)h * Hd + c1];
        #pragma unroll
        for (int rr = 0; rr < 16; ++rr) {
            float a = As[rr][h];
            acc0[rr] += a * w0;
            acc1[rr] += a * w1;
        }
    }
    for (int rr = 0; rr < 16; ++rr) {
        Wctx[(size_t)(r0 + rr) * Hd + c0] = acc0[rr];
        Wctx[(size_t)(r0 + rr) * Hd + c1] = acc1[rr];
    }
}

// ---------------- rwh[t*256+row][k] = fp16( sum_h resp[r,t,b,h] * Wt[h,k] ) ----------------
__global__ __launch_bounds__(256) void k_rw(const float* __restrict__ resp,
                                            const float* __restrict__ Wt,
                                            unsigned short* __restrict__ rwh) {
    __shared__ float As[16][Hd];
    int gr0 = blockIdx.x * 16;
    int tid = threadIdx.x;
    for (int rr = 0; rr < 16; ++rr) {
        int gr = gr0 + rr;
        int t = gr >> 8, row = gr & 255;
        int r = row >> 6, bb = row & 63;
        const float* src = resp + (((size_t)(r * Wd + t)) * Bd + bb) * Hd;
        for (int h = tid; h < Hd; h += 256) As[rr][h] = src[h];
    }
    __syncthreads();
    int c0 = tid, c1 = tid + 256;
    float acc0[16], acc1[16];
    #pragma unroll
    for (int rr = 0; rr < 16; ++rr) { acc0[rr] = 0.f; acc1[rr] = 0.f; }
    for (int h = 0; h < Hd; ++h) {
        float w0 = Wt[(size_t)h * Hd + c0], w1 = Wt[(size_t)h * Hd + c1];
        #pragma unroll
        for (int rr = 0; rr < 16; ++rr) {
            float a = As[rr][h];
            acc0[rr] += a * w0;
            acc1[rr] += a * w1;
        }
    }
    for (int rr = 0; rr < 16; ++rr) {
        rwh[(size_t)(gr0 + rr) * Hd + c0] =
            __builtin_bit_cast(unsigned short, (_Float16)acc0[rr]);
        rwh[(size_t)(gr0 + rr) * Hd + c1] =
            __builtin_bit_cast(unsigned short, (_Float16)acc1[rr]);
    }
}

// ---------------- persistent scan: 256 blocks (one per (r,b)), 1024 threads ----------------
// Each block owns one independent (r,b) recurrence -> all 256 CUs active.
// ctx[b] (64 KB) and Wctx[b] (64 KB) LDS-resident for the whole scan; WA streamed
// as packed fp16 (1 MB/step/CU, the per-CU floor). 4 barriers/step.
__global__ __launch_bounds__(1024, 4) void k_scan(
    const float* __restrict__ ctx,      // (P,B,H)
    const unsigned short* __restrict__ rwh, // (W*256, H) fp16
    const unsigned* __restrict__ WAp,   // (H/2, 1024) half2 pairs along h
    const float* __restrict__ Wctx,     // (B*P, H)
    const float* __restrict__ walpha,   // (H)
    const float* __restrict__ hidden,   // (R,B,H)
    const float* __restrict__ lin_p,    // (H,H) row-major, row = out col
    const float* __restrict__ lin_x,    // (H,H)
    float* __restrict__ out_resp,       // (R,B,H)
    float* __restrict__ out_alpha)      // (R,W,B,P)
{
    extern __shared__ float dynS[];
    float* sCtx   = dynS;                          // [32][512] 64 KB (persistent)
    float* sWctx  = dynS + 16384;                  // [32][512] 64 KB (persistent)
    float* sPart  = dynS + 32768;                  // [4][1024] 16 KB (epilogue reuse)
    float* sW     = dynS + 36864;                  // [1024]     4 KB
    float* sAtten = dynS + 37888;                  // [512]      2 KB (fp32, epilogue)
    unsigned* sAttenH = (unsigned*)(dynS + 38400); // [256]      1 KB (half2 pairs)
    __shared__ float sWal[Hd];                     //  2 KB
    __shared__ float scS[Pd];                      //  128 B

    const int bid = blockIdx.x;
    const int r_ = bid >> 6, b_ = bid & 63;
    const int tid = threadIdx.x;

    // ---- preamble: ctx[b], Wctx[b], walpha -> LDS ----
    for (int i = tid; i < 4096; i += 1024) {
        int p = i >> 7, h4 = (i & 127) << 2;
        *(float4*)&sCtx[(p << 9) + h4] =
            *(const float4*)&ctx[((size_t)(p * Bd + b_)) * Hd + h4];
        *(float4*)&sWctx[(p << 9) + h4] =
            *(const float4*)&Wctx[((size_t)(b_ * Pd + p)) * Hd + h4];
    }
    if (tid < Hd) sWal[tid] = walpha[tid];
    if (tid < 256) sAttenH[tid] = 0u;
    __syncthreads();

    // ---- identities ----
    const int qid = tid >> 8;                 // h-quarter 0..3 (64 h2 each)
    const int cq  = (tid & 255) << 2;         // col quad 0..1020
    const unsigned* __restrict__ wap = WAp + ((size_t)(qid << 6) << 10) + cq;
    const unsigned* __restrict__ ah  = sAttenH + (qid << 6);

    const int pB = tid >> 5, hcB = tid & 31;  // score: 32 threads per p

    for (int t = 0; t < Wd; ++t) {
        // rw prefetch for this thread's reduce column (latency hides under A)
        float rwf = 0.f;
        if (tid < Hd) {
            unsigned short u = rwh[((size_t)(t * 256 + bid) << 9) + tid];
            rwf = (float)__builtin_bit_cast(_Float16, u);
        }

        // ---- A: GEMV quarter  w(cq..cq+3) over h2 in [qid*64, qid*64+64) ----
        if (t > 0) {
            float4 acc = make_float4(0.f, 0.f, 0.f, 0.f);
            #pragma unroll 4
            for (int jq = 0; jq < 16; ++jq) {
                const unsigned* wq = wap + ((size_t)jq << 12);
                uint4 w0 = *(const uint4*)(wq);
                uint4 w1 = *(const uint4*)(wq + 1024);
                uint4 w2 = *(const uint4*)(wq + 2048);
                uint4 w3 = *(const uint4*)(wq + 3072);
                uint4 a4 = *(const uint4*)(ah + (jq << 2));
                acc.x = d2(a4.x, w0.x, acc.x); acc.y = d2(a4.x, w0.y, acc.y);
                acc.z = d2(a4.x, w0.z, acc.z); acc.w = d2(a4.x, w0.w, acc.w);
                acc.x = d2(a4.y, w1.x, acc.x); acc.y = d2(a4.y, w1.y, acc.y);
                acc.z = d2(a4.y, w1.z, acc.z); acc.w = d2(a4.y, w1.w, acc.w);
                acc.x = d2(a4.z, w2.x, acc.x); acc.y = d2(a4.z, w2.y, acc.y);
                acc.z = d2(a4.z, w2.z, acc.z); acc.w = d2(a4.z, w2.w, acc.w);
                acc.x = d2(a4.w, w3.x, acc.x); acc.y = d2(a4.w, w3.y, acc.y);
                acc.z = d2(a4.w, w3.z, acc.z); acc.w = d2(a4.w, w3.w, acc.w);
            }
            *(float4*)&sPart[(qid << 10) + cq] = acc;
            __syncthreads();
        }

        // ---- reduce split-K partials + rw -> sW (col = tid) ----
        {
            float s = rwf;
            if (t > 0)
                s += sPart[tid] + sPart[1024 + tid] + sPart[2048 + tid] + sPart[3072 + tid];
            sW[tid] = s;
        }
        __syncthreads();

        // ---- B: score[p] = sum_h tanh(Wctx[p,h]+w[h])*walpha[h] ----
        {
            const float* __restrict__ wrow = sWctx + (pB << 9);
            float sc = 0.f;
            #pragma unroll
            for (int k = 0; k < 4; ++k) {
                int h4 = (k << 7) + (hcB << 2);
                float4 wc  = *(const float4*)&wrow[h4];
                float4 wal = *(const float4*)&sWal[h4];
                float4 v   = *(const float4*)&sW[h4];
                sc += tanh_fast(wc.x+v.x)*wal.x + tanh_fast(wc.y+v.y)*wal.y
                    + tanh_fast(wc.z+v.z)*wal.z + tanh_fast(wc.w+v.w)*wal.w;
            }
            #pragma unroll
            for (int off = 16; off; off >>= 1) sc += __shfl_down(sc, off, 32);
            if (hcB == 0) scS[pB] = sc;
        }
        __syncthreads();

        // ---- C+D: in-register softmax, alpha write, atten update ----
        if (tid < Hd) {
            float sv[Pd];
            #pragma unroll
            for (int p = 0; p < Pd; ++p) sv[p] = scS[p];
            float m = sv[0];
            #pragma unroll
            for (int p = 1; p < Pd; ++p) m = fmaxf(m, sv[p]);
            float sum = 0.f;
            #pragma unroll
            for (int p = 0; p < Pd; ++p) { sv[p] = __expf(sv[p] - m); sum += sv[p]; }
            float inv = __fdividef(1.f, sum);
            if (tid < Pd)
                out_alpha[(((size_t)r_ * Wd + t) * Bd + b_) * Pd + tid] = sv[tid] * inv;
            float a = 0.f;
            #pragma unroll 8
            for (int p = 0; p < Pd; ++p) a += sv[p] * sCtx[(p << 9) + tid];
            a = a * inv + tanh_fast(sW[Hd + tid]);
            sAtten[tid] = a;
            float an = __shfl_down(a, 1, 64);
            if (!(tid & 1)) {
                h2v ph; ph.x = (_Float16)a; ph.y = (_Float16)an;
                sAttenH[tid >> 1] = __builtin_bit_cast(unsigned, ph);
            }
        }
        __syncthreads();
    }

    // ---- epilogue: resp_c row = tanh(atten@lin_p^T + hidden@lin_x^T) ----
    if (tid < Hd) sPart[tid] = hidden[((size_t)(r_ * Bd + b_)) * Hd + tid];
    __syncthreads();
    {
        const int half = tid >> 9;             // h-half 0..1
        const int c = tid & 511;
        const int hb = half << 8;              // 256 h per half
        const float* __restrict__ lp = lin_p + (size_t)c * Hd + hb;
        const float* __restrict__ lx = lin_x + (size_t)c * Hd + hb;
        float f = 0.f;
        #pragma unroll 2
        for (int h = 0; h < 256; h += 4) {
            float4 lpv = *(const float4*)(lp + h);
            float4 lxv = *(const float4*)(lx + h);
            float4 aa  = *(const float4*)&sAtten[hb + h];
            float4 hh  = *(const float4*)&sPart[hb + h];
            f += aa.x*lpv.x + aa.y*lpv.y + aa.z*lpv.z + aa.w*lpv.w
               + hh.x*lxv.x + hh.y*lxv.y + hh.z*lxv.z + hh.w*lxv.w;
        }
        sPart[1024 + (half << 9) + c] = f;
    }
    __syncthreads();
    if (tid < Hd) {
        float f = sPart[1024 + tid] + sPart[1536 + tid];
        out_resp[((size_t)(r_ * Bd + b_)) * Hd + tid] = tanh_fast(f);
    }
}

extern "C" void kernel_launch(void* const* d_in, const int* in_sizes, int n_in,
                              void* d_out, int out_size, void* d_ws, size_t ws_size,
                              hipStream_t stream) {
    const float* ctx    = (const float*)d_in[0];  // (P,B,H)
    const float* resp   = (const float*)d_in[1];  // (R,W,B,H)
    const float* hidden = (const float*)d_in[2];  // (R,B,H)
    const float* Wc     = (const float*)d_in[3];
    const float* Wt     = (const float*)d_in[4];
    const float* Wa     = (const float*)d_in[5];
    const float* Walpha = (const float*)d_in[6];  // (H,1)
    const float* lin_w  = (const float*)d_in[7];
    const float* lin_p  = (const float*)d_in[8];
    const float* lin_x  = (const float*)d_in[9];

    float* out = (float*)d_out;
    float* resp_c_out = out;                       // R*B*H = 131072
    float* alpha_out  = out + Rd * Bd * Hd;        // R*W*B*P = 524288

    float* ws   = (float*)d_ws;
    float* WAc  = ws;                              //   524288 floats (512x1024 fp32)
    float* Wctx = ws + 524288;                     //  1048576 floats
    unsigned short* rwh = (unsigned short*)(ws + 1572864); // 8388608 ushorts
    unsigned* WAp = (unsigned*)(ws + 5767168);     //   262144 uints (256x1024 half2)

    dim3 g16(16, 16);
    k_prep_wa<<<g16, 256, 0, stream>>>(Wa, lin_w, WAc);
    k_pack<<<1024, 256, 0, stream>>>(WAc, WAp);
    k_wctx<<<128, 256, 0, stream>>>(ctx, Wc, Wctx);
    k_rw<<<1024, 256, 0, stream>>>(resp, Wt, rwh);

    const int dyn_lds = 154624;                    // 38656 floats (~151 KB)
    static bool s_attr = false;
    if (!s_attr) {
        hipFuncSetAttribute((const void*)k_scan,
                            hipFuncAttributeMaxDynamicSharedMemorySize, dyn_lds);
        s_attr = true;
    }
    k_scan<<<256, 1024, dyn_lds, stream>>>(ctx, rwh, WAp, Wctx, Walpha, hidden,
                                           lin_p, lin_x, resp_c_out, alpha_out);
}